// Round 8
// baseline (2557.353 us; speedup 1.0000x reference)
//
#include <hip/hip_runtime.h>
#include <hip/hip_bf16.h>

typedef __hip_bfloat16 bf16;
typedef unsigned short u16;
typedef unsigned long long u64;
using frag  = __attribute__((ext_vector_type(8))) short;   // 8 bf16
using f32x4 = __attribute__((ext_vector_type(4))) float;   // 4 fp32 acc

static constexpr int T_  = 128;
static constexpr int B_  = 512;
static constexpr int H_  = 512;
static constexpr int K_  = 512;
static constexpr int G4_ = 2048;
static constexpr int NWG = 256;

// dynamic LDS: weights 128KB (frag-blocked) + xchg 16KB (gate exchange / h transpose)
static constexpr size_t W_BYTES    = 131072;
static constexpr size_t XCHG_BYTES = 16384;
static constexpr size_t SMEM_BYTES = W_BYTES + XCHG_BYTES;   // 147456

// L3-coherent u64 load (L1+L2 bypass) — used only in the coalesced copy stage
__device__ __forceinline__ u64 ld_coh64(const u64* p) {
  return __hip_atomic_load(p, __ATOMIC_RELAXED, __HIP_MEMORY_SCOPE_AGENT);
}

// sc0 load: bypass L1, cache in local L2 (XCD-local broadcast medium)
__device__ __forceinline__ frag ld_a_sc0(const u16* p) {
  frag r;
  asm volatile("global_load_dwordx4 %0, %1, off sc0" : "=v"(r) : "v"(p));
  return r;
}

// ---------------- setup kernels ----------------

__global__ void k_f32_to_bf16_v4(const float4* __restrict__ src,
                                 ushort4* __restrict__ dst, int n4) {
  int i = blockIdx.x * blockDim.x + threadIdx.x;
  int stride = gridDim.x * blockDim.x;
  for (; i < n4; i += stride) {
    float4 v = src[i];
    ushort4 o;
    bf16 t0 = __float2bfloat16(v.x); o.x = *reinterpret_cast<u16*>(&t0);
    bf16 t1 = __float2bfloat16(v.y); o.y = *reinterpret_cast<u16*>(&t1);
    bf16 t2 = __float2bfloat16(v.z); o.z = *reinterpret_cast<u16*>(&t2);
    bf16 t3 = __float2bfloat16(v.w); o.w = *reinterpret_cast<u16*>(&t3);
    dst[i] = o;
  }
}

__global__ void k_bias(const float* __restrict__ bih0, const float* __restrict__ bhh0,
                       const float* __restrict__ bih1, const float* __restrict__ bhh1,
                       float* __restrict__ bsum0, float* __restrict__ bsum1) {
  int i = blockIdx.x * blockDim.x + threadIdx.x;
  if (i < G4_) {
    bsum0[i] = bih0[i] + bhh0[i];
    bsum1[i] = bih1[i] + bhh1[i];
  }
}

__global__ void k_zero(int* p) {
  int i = blockIdx.x * blockDim.x + threadIdx.x;
  if (i < 256) p[i] = 0;
}

// ---------------- persistent LSTM kernel ----------------
// 256 WGs x 512 thr (8 waves). XCD-locality: lb = wg&7 -> layer = lb>>2, bg = lb&3;
// cg = wg>>3 (0..31). WG owns batch rows [bg*128,+128) x h-cols [cg*16,+16).
// Waves: wave = rg*2 + nh; rg 0..3 -> rows [rg*32,+32) (mi 0..1 = 16-row halves);
// nh 0..1 -> gate pair {0,1} or {2,3}. Each wave: 128 MFMA, 64 B ds_reads (M_rep=2).
// Weights frag-blocked in LDS (conflict-free b128). Gate halves exchanged via LDS.
// h exchange:  h-self -> bufA (normal stores, sc0 reads: XCD-local L2, no L3);
//              layer0 h0 additionally -> h0buf (coherent, L3) consumed by layer1
//              via a per-phase coalesced 32-WG copy into Xstage (local L2).
// Barriers: relaxed-atomic counters, no cache-maintenance fences anywhere.
__global__ __launch_bounds__(512, 2)
void k_main(const u16* __restrict__ latb,
            const u16* __restrict__ W0i, const u16* __restrict__ W0h,
            const u16* __restrict__ W1i, const u16* __restrict__ W1h,
            const float* __restrict__ bs0, const float* __restrict__ bs1,
            const int* __restrict__ reset,   // (T,B)
            const float* __restrict__ h0in,  // (2,B,H) initial h
            const float* __restrict__ c0,    // (2,B,H) initial c
            u16* __restrict__ h0buf,         // [2][B][H] coherent cross-layer h0
            u16* __restrict__ bufA0,         // [2][B][H] layer0 h-self (L2-local)
            u16* __restrict__ bufA1,         // [2][B][H] layer1 h-self (L2-local)
            u16* __restrict__ xstage,        // [4 bg][2][128][512] layer1 X staging
            float* __restrict__ hidden,      // (T,B,H)
            float* __restrict__ hn,          // (2,B,H)
            float* __restrict__ cn,          // (2,B,H)
            int* __restrict__ ctr) {         // 256 ints
  extern __shared__ char smem_raw[];
  u16*   wlds = (u16*)smem_raw;                 // 128KB frag-blocked weights
  float* xch  = (float*)(smem_raw + W_BYTES);   // 16KB exchange / transpose
  __shared__ int rstlds[128];

  const int tid   = threadIdx.x;
  const int wg    = blockIdx.x;
  const int lb    = wg & 7;
  const int layer = lb >> 2;
  const int bg    = lb & 3;
  const int cg    = wg >> 3;
  const int hbase = cg * 16;
  const int rowbase = bg * 128;
  const int wave  = tid >> 6;                  // 0..7
  const int lane  = tid & 63;
  const int r16   = lane & 15;
  const int kq    = lane >> 4;                 // 0..3
  const int rg    = wave >> 1;                 // row-group 0..3
  const int nh    = wave & 1;                  // gate-pair: {0,1} or {2,3}
  const int nh2   = nh * 2;

  const u16* Wih = layer ? W1i : W0i;
  const u16* Whh = layer ? W1h : W0h;
  const float* bs = layer ? bs1 : bs0;
  u16* bufA_self = layer ? bufA1 : bufA0;
  u16* xst_self  = xstage + (size_t)bg * 2 * 128 * 512;
  int* ctrSelf  = ctr + bg * 32 + (layer ? 16 : 0);
  int* ctrOther = ctr + bg * 32 + (layer ? 0 : 16);
  int* ctrCopy  = ctr + 128 + bg * 16;

  // ---- stage weights into frag-blocked LDS (once) ----
  // chunk c = fb*64 + l ; fb = ni*32 + kslot ; kslot<16 -> W_ih, else W_hh
  // lane l holds W[gate ni, col hbase+(l&15)][kslot_local*32 + (l>>4)*8 .. +7]
  for (int it = 0; it < 16; ++it) {
    int c = it * 512 + tid;                    // 0..8191
    int fb = c >> 6, l = c & 63;
    int ni = fb >> 5, kslot = fb & 31;
    int col = hbase + (l & 15);
    int klocal = (kslot & 15) * 32 + (l >> 4) * 8;
    const u16* M = (kslot < 16) ? Wih : Whh;
    const u16* src = M + (size_t)(ni * H_ + col) * K_ + klocal;
    *(float4*)(wlds + ((size_t)c) * 8) = *(const float4*)src;
  }

  // ---- in-kernel bufA init (owning WG writes its own rows/cols: correct XCD) ----
  {
    const int initpar = layer;     // L0 reads par0 at p=0; L1 reads par1 at p=1
    #pragma unroll
    for (int q = 0; q < 4; ++q) {
      int idx = q * 512 + tid;               // 0..2047
      int rrow = idx >> 4;                   // 0..127
      int ccol = idx & 15;
      float hv = h0in[(size_t)layer * B_ * H_ + (size_t)(rowbase + rrow) * H_ + hbase + ccol];
      bf16 hbv = __float2bfloat16(hv);
      bufA_self[(size_t)initpar * B_ * H_ + (size_t)(rowbase + rrow) * H_ + hbase + ccol] =
          *reinterpret_cast<u16*>(&hbv);
    }
  }

  // per-lane gate biases (col = hbase + r16)
  float bias[4];
  #pragma unroll
  for (int g = 0; g < 4; ++g) bias[g] = bs[g * H_ + hbase + r16];

  // c-state: this wave's elementwise rows = rg*32 + nh*16 + kq*4 + j
  float creg[4];
  #pragma unroll
  for (int j = 0; j < 4; ++j)
    creg[j] = c0[((size_t)layer * B_ + (rowbase + rg * 32 + nh * 16 + kq * 4 + j)) * H_
                 + hbase + r16];

  // ---- init barrier (epoch 1): bufA init visible XCD-wide before first compute ----
  asm volatile("s_waitcnt vmcnt(0)" ::: "memory");
  __syncthreads();
  if (tid == 0)
    __hip_atomic_fetch_add(ctrSelf, 1, __ATOMIC_RELAXED, __HIP_MEMORY_SCOPE_AGENT);
  if (tid == 0) {
    while (true) {
      int a = __hip_atomic_load(ctrSelf,  __ATOMIC_RELAXED, __HIP_MEMORY_SCOPE_AGENT);
      int b = __hip_atomic_load(ctrOther, __ATOMIC_RELAXED, __HIP_MEMORY_SCOPE_AGENT);
      if (a >= 32 && b >= 32) break;
      __builtin_amdgcn_s_sleep(2);
    }
  }
  __syncthreads();

  for (int p = 0; p <= T_; ++p) {
    const int t = layer ? (p - 1) : p;
    const bool active = (t >= 0 && t < T_);
    float hnew_r[4], cnew_r[4];
    float4 hv4;
    int ewrow = 0;
    const int pc4 = lane & 3, prow = lane >> 2;

    if (active) {
      if (tid < 128) rstlds[tid] = reset[(size_t)t * B_ + rowbase + tid];
      __syncthreads();

      // ---- layer1: coalesced copy h0buf(L3) -> Xstage (local L2), then copy-barrier
      if (layer) {
        const u64* src = (const u64*)(h0buf + (size_t)(p & 1) * B_ * H_);
        u64* dst = (u64*)(xst_self + (size_t)(p & 1) * 128 * 512);
        int r = tid >> 7;               // 0..3 local row within this WG's 4-row slice
        int cqw = tid & 127;            // u64 index within row (128 per row)
        int lrow = cg * 4 + r;          // 0..127 local row in bg-block
        u64 v = ld_coh64(src + ((size_t)(rowbase + lrow) * H_) / 4 + cqw);
        dst[(size_t)lrow * 128 + cqw] = v;                  // normal -> local L2
        asm volatile("s_waitcnt vmcnt(0)" ::: "memory");
        __syncthreads();
        if (tid == 0)
          __hip_atomic_fetch_add(ctrCopy, 1, __ATOMIC_RELAXED, __HIP_MEMORY_SCOPE_AGENT);
        if (tid == 0) {
          const int target = 32 * p;    // p copies so far (p >= 1 here)
          while (__hip_atomic_load(ctrCopy, __ATOMIC_RELAXED, __HIP_MEMORY_SCOPE_AGENT) < target)
            __builtin_amdgcn_s_sleep(2);
        }
        __syncthreads();
      }

      // ---- A-frag bases (x-part s<16, h-part s>=16), all sc0 loads ----
      const int lrow0 = rg * 32 + r16;
      const u16* xbase = layer ? (xst_self + (size_t)(p & 1) * 128 * 512)
                               : (latb + (size_t)t * B_ * K_ + (size_t)rowbase * K_);
      const u16* hbA = bufA_self + (size_t)(p & 1) * B_ * H_ + (size_t)rowbase * H_;
      const u16* xb[2], *hb[2];
      xb[0] = xbase + (size_t)lrow0 * K_ + kq * 8;
      xb[1] = xbase + (size_t)(lrow0 + 16) * K_ + kq * 8;
      hb[0] = hbA + (size_t)lrow0 * H_ + kq * 8;
      hb[1] = hbA + (size_t)(lrow0 + 16) * H_ + kq * 8;
      const bool ra0 = rstlds[rg * 32 + r16] != 0;
      const bool ra1 = rstlds[rg * 32 + 16 + r16] != 0;

      f32x4 acc[2][2] = {};
      const frag zf = {};
      frag a[2][2][4];

#define ISSUE_CHUNK(CP, CBASE)                                               \
      _Pragma("unroll")                                                      \
      for (int si = 0; si < 4; ++si) {                                       \
        const int s = (CBASE) * 4 + si;                                      \
        const u16* pa0 = (s < 16) ? (xb[0] + s * 32) : (hb[0] + (s - 16) * 32); \
        const u16* pa1 = (s < 16) ? (xb[1] + s * 32) : (hb[1] + (s - 16) * 32); \
        a[CP][0][si] = ld_a_sc0(pa0);                                        \
        a[CP][1][si] = ld_a_sc0(pa1);                                        \
      }

#define CONSUME_CHUNK(CP, CBASE)                                             \
      _Pragma("unroll")                                                      \
      for (int si = 0; si < 4; ++si) {                                       \
        const int s = (CBASE) * 4 + si;                                      \
        frag av0 = a[CP][0][si], av1 = a[CP][1][si];                         \
        if (s >= 16) { if (ra0) av0 = zf; if (ra1) av1 = zf; }               \
        _Pragma("unroll")                                                    \
        for (int g = 0; g < 2; ++g) {                                        \
          frag b = *reinterpret_cast<const frag*>(                           \
              wlds + ((size_t)(((nh2 + g) * 32 + s) * 64 + lane)) * 8);      \
          acc[0][g] = __builtin_amdgcn_mfma_f32_16x16x32_bf16(av0, b, acc[0][g], 0, 0, 0); \
          acc[1][g] = __builtin_amdgcn_mfma_f32_16x16x32_bf16(av1, b, acc[1][g], 0, 0, 0); \
        }                                                                    \
      }

      ISSUE_CHUNK(0, 0)
      ISSUE_CHUNK(1, 1)
      #pragma unroll
      for (int c = 0; c < 8; ++c) {
        if (c < 7) { asm volatile("s_waitcnt vmcnt(8)" ::: "memory"); }
        else       { asm volatile("s_waitcnt vmcnt(0)" ::: "memory"); }
        __builtin_amdgcn_sched_barrier(0);
        if ((c & 1) == 0) {
          CONSUME_CHUNK(0, c)
          if (c < 6) { ISSUE_CHUNK(0, c + 2) }
        } else {
          CONSUME_CHUNK(1, c)
          if (c < 6) { ISSUE_CHUNK(1, c + 2) }
        }
      }
#undef ISSUE_CHUNK
#undef CONSUME_CHUNK

      // ---- gate-pair exchange: each wave passes its other-mi half to partner ----
      *(f32x4*)(xch + ((size_t)(wave * 2 + 0) * 64 + lane) * 4) = acc[1 - nh][0];
      *(f32x4*)(xch + ((size_t)(wave * 2 + 1) * 64 + lane) * 4) = acc[1 - nh][1];
      __syncthreads();
      const int w2 = rg * 2 + (1 - nh);
      f32x4 rg0 = *(const f32x4*)(xch + ((size_t)(w2 * 2 + 0) * 64 + lane) * 4);
      f32x4 rg1 = *(const f32x4*)(xch + ((size_t)(w2 * 2 + 1) * 64 + lane) * 4);
      __syncthreads();   // xchg fully read before region reuse as hstage

      // ---- elementwise for this wave's 16 rows (mi = nh) ----
      float* hst = xch + (size_t)wave * 512;    // reuse: [16][20] f32
      #pragma unroll
      for (int j = 0; j < 4; ++j) {
        const int lrow = rg * 32 + nh * 16 + kq * 4 + j;
        float G0, G1, G2, G3;
        if (nh == 0) { G0 = acc[0][0][j]; G1 = acc[0][1][j]; G2 = rg0[j]; G3 = rg1[j]; }
        else         { G0 = rg0[j]; G1 = rg1[j]; G2 = acc[1][0][j]; G3 = acc[1][1][j]; }
        float gi = G0 + bias[0];
        float gf = G1 + bias[1];
        float gg = G2 + bias[2];
        float go = G3 + bias[3];
        float iv = 1.f / (1.f + __expf(-gi));
        float fv = 1.f / (1.f + __expf(-gf));
        float gv = 1.f - 2.f / (__expf(2.f * gg) + 1.f);   // tanh
        float ov = 1.f / (1.f + __expf(-go));
        float ce = rstlds[lrow] ? 0.f : creg[j];
        float cnew = fv * ce + iv * gv;
        float hnew = ov * (1.f - 2.f / (__expf(2.f * cnew) + 1.f));
        creg[j] = cnew;
        cnew_r[j] = cnew;
        hnew_r[j] = hnew;
        hst[(kq * 4 + j) * 20 + r16] = hnew;    // wave-local transpose tile
      }

      // ---- pack + h stores (in-wave LDS transpose; DS ops in-order per wave) ----
      hv4 = *(const float4*)(hst + prow * 20 + pc4 * 4);
      ewrow = rowbase + rg * 32 + nh * 16 + prow;
      bf16 pb0 = __float2bfloat16(hv4.x), pb1 = __float2bfloat16(hv4.y);
      bf16 pb2 = __float2bfloat16(hv4.z), pb3 = __float2bfloat16(hv4.w);
      u64 pk = (u64)*reinterpret_cast<u16*>(&pb0)
             | ((u64)*reinterpret_cast<u16*>(&pb1) << 16)
             | ((u64)*reinterpret_cast<u16*>(&pb2) << 32)
             | ((u64)*reinterpret_cast<u16*>(&pb3) << 48);
      const size_t hoff = (size_t)ewrow * H_ + hbase + pc4 * 4;
      *(u64*)(bufA_self + (size_t)((p + 1) & 1) * B_ * H_ + hoff) = pk;   // normal -> local L2
      if (layer == 0) {
        __hip_atomic_store((u64*)(h0buf + (size_t)((p + 1) & 1) * B_ * H_ + hoff), pk,
                           __ATOMIC_RELAXED, __HIP_MEMORY_SCOPE_AGENT);   // coherent -> L3
      }
    }

    // ---- main pair-domain barrier: arrive ----
    if (p < T_) {
      asm volatile("s_waitcnt vmcnt(0)" ::: "memory");
      __syncthreads();
      if (tid == 0)
        __hip_atomic_fetch_add(ctrSelf, 1, __ATOMIC_RELAXED, __HIP_MEMORY_SCOPE_AGENT);
    }

    // ---- deferred output stores (overlap with barrier poll; no in-kernel readers)
    if (active) {
      if (layer)
        *(float4*)(hidden + (size_t)t * B_ * H_ + (size_t)ewrow * H_ + hbase + pc4 * 4) = hv4;
      if (t == T_ - 1) {
        #pragma unroll
        for (int j = 0; j < 4; ++j) {
          const size_t off = (size_t)(rowbase + rg * 32 + nh * 16 + kq * 4 + j) * H_
                             + hbase + r16;
          hn[(size_t)layer * B_ * H_ + off] = hnew_r[j];
          cn[(size_t)layer * B_ * H_ + off] = cnew_r[j];
        }
      }
    }

    // ---- main barrier: wait (epoch = p+2: init + phases 0..p) ----
    if (p < T_) {
      if (tid == 0) {
        const int target = 32 * (p + 2);
        while (true) {
          int a = __hip_atomic_load(ctrSelf,  __ATOMIC_RELAXED, __HIP_MEMORY_SCOPE_AGENT);
          int b = __hip_atomic_load(ctrOther, __ATOMIC_RELAXED, __HIP_MEMORY_SCOPE_AGENT);
          if (a >= target && b >= target) break;
          __builtin_amdgcn_s_sleep(2);
        }
      }
      __syncthreads();
    }
  }
}

// ---------------- host ----------------

extern "C" void kernel_launch(void* const* d_in, const int* in_sizes, int n_in,
                              void* d_out, int out_size, void* d_ws, size_t ws_size,
                              hipStream_t stream) {
  (void)in_sizes; (void)n_in; (void)out_size; (void)ws_size;

  const float* latent = (const float*)d_in[0];
  const float* h0in   = (const float*)d_in[1];
  const float* c0in   = (const float*)d_in[2];
  const int*   reset  = (const int*)d_in[3];
  const float* W_ih0  = (const float*)d_in[4];
  const float* W_hh0  = (const float*)d_in[5];
  const float* b_ih0  = (const float*)d_in[6];
  const float* b_hh0  = (const float*)d_in[7];
  const float* W_ih1  = (const float*)d_in[8];
  const float* W_hh1  = (const float*)d_in[9];
  const float* b_ih1  = (const float*)d_in[10];
  const float* b_hh1  = (const float*)d_in[11];

  float* out    = (float*)d_out;
  float* hidden = out;                               // (T,B,H)
  float* hn     = out + (size_t)T_ * B_ * H_;        // (2,B,H)
  float* cn     = hn + (size_t)2 * B_ * H_;          // (2,B,H)

  // workspace layout
  char* ws = (char*)d_ws;
  u16* latb  = (u16*)ws;                             // T*B*K bf16 (64 MiB)
  u16* wih0b = latb + (size_t)T_ * B_ * K_;
  u16* whh0b = wih0b + (size_t)G4_ * K_;
  u16* wih1b = whh0b + (size_t)G4_ * K_;
  u16* whh1b = wih1b + (size_t)G4_ * K_;
  float* bsum0 = (float*)(whh1b + (size_t)G4_ * K_);
  float* bsum1 = bsum0 + G4_;
  u16* h0buf = (u16*)(bsum1 + G4_);                  // [2][B][H] coherent
  u16* bufA0 = h0buf + (size_t)2 * B_ * H_;          // [2][B][H] L2-local
  u16* bufA1 = bufA0 + (size_t)2 * B_ * H_;          // [2][B][H] L2-local
  u16* xstage = bufA1 + (size_t)2 * B_ * H_;         // [4][2][128][512]
  int* ctr   = (int*)(xstage + (size_t)4 * 2 * 128 * 512);  // 256 ints

  // conversions / init (stream-ordered)
  int n_lat4 = T_ * B_ * K_ / 4;
  k_f32_to_bf16_v4<<<2048, 256, 0, stream>>>((const float4*)latent, (ushort4*)latb, n_lat4);
  int n_w4 = G4_ * K_ / 4;
  k_f32_to_bf16_v4<<<256, 256, 0, stream>>>((const float4*)W_ih0, (ushort4*)wih0b, n_w4);
  k_f32_to_bf16_v4<<<256, 256, 0, stream>>>((const float4*)W_hh0, (ushort4*)whh0b, n_w4);
  k_f32_to_bf16_v4<<<256, 256, 0, stream>>>((const float4*)W_ih1, (ushort4*)wih1b, n_w4);
  k_f32_to_bf16_v4<<<256, 256, 0, stream>>>((const float4*)W_hh1, (ushort4*)whh1b, n_w4);
  k_bias<<<(G4_ + 255) / 256, 256, 0, stream>>>(b_ih0, b_hh0, b_ih1, b_hh1, bsum0, bsum1);
  k_zero<<<1, 256, 0, stream>>>(ctr);

  // persistent cooperative kernel
  hipFuncSetAttribute((const void*)k_main, hipFuncAttributeMaxDynamicSharedMemorySize,
                      (int)SMEM_BYTES);
  void* args[] = { (void*)&latb, (void*)&wih0b, (void*)&whh0b, (void*)&wih1b, (void*)&whh1b,
                   (void*)&bsum0, (void*)&bsum1, (void*)&reset, (void*)&h0in, (void*)&c0in,
                   (void*)&h0buf, (void*)&bufA0, (void*)&bufA1, (void*)&xstage,
                   (void*)&hidden, (void*)&hn, (void*)&cn, (void*)&ctr };
  hipLaunchCooperativeKernel((void*)k_main, dim3(NWG), dim3(512), args,
                             (unsigned int)SMEM_BYTES, stream);
}

// Round 9
// 2098.493 us; speedup vs baseline: 1.2187x; 1.2187x over previous
//
#include <hip/hip_runtime.h>
#include <hip/hip_bf16.h>

typedef __hip_bfloat16 bf16;
typedef unsigned short u16;
typedef unsigned long long u64;
using frag  = __attribute__((ext_vector_type(8))) short;   // 8 bf16
using f32x4 = __attribute__((ext_vector_type(4))) float;   // 4 fp32 acc

static constexpr int T_  = 128;
static constexpr int B_  = 512;
static constexpr int H_  = 512;
static constexpr int K_  = 512;
static constexpr int G4_ = 2048;
static constexpr int NWG = 256;

// dynamic LDS: frag-blocked weights only
static constexpr size_t W_BYTES = 131072;                  // 128 blocks x 1KB
static constexpr size_t SMEM_BYTES = W_BYTES;

// coherent (agent-scope, L1/L2-bypassing) 16B load as 2x b64 relaxed atomics
__device__ __forceinline__ frag ld_coh(const u16* p) {
  u64 lo = __hip_atomic_load((const u64*)p,       __ATOMIC_RELAXED, __HIP_MEMORY_SCOPE_AGENT);
  u64 hi = __hip_atomic_load((const u64*)(p + 4), __ATOMIC_RELAXED, __HIP_MEMORY_SCOPE_AGENT);
  union { u64 q[2]; frag f; } u;
  u.q[0] = lo; u.q[1] = hi;
  return u.f;
}

// ---------------- setup kernels ----------------

__global__ void k_f32_to_bf16_v4(const float4* __restrict__ src,
                                 ushort4* __restrict__ dst, int n4) {
  int i = blockIdx.x * blockDim.x + threadIdx.x;
  int stride = gridDim.x * blockDim.x;
  for (; i < n4; i += stride) {
    float4 v = src[i];
    ushort4 o;
    bf16 t0 = __float2bfloat16(v.x); o.x = *reinterpret_cast<u16*>(&t0);
    bf16 t1 = __float2bfloat16(v.y); o.y = *reinterpret_cast<u16*>(&t1);
    bf16 t2 = __float2bfloat16(v.z); o.z = *reinterpret_cast<u16*>(&t2);
    bf16 t3 = __float2bfloat16(v.w); o.w = *reinterpret_cast<u16*>(&t3);
    dst[i] = o;
  }
}

__global__ void k_bias(const float* __restrict__ bih0, const float* __restrict__ bhh0,
                       const float* __restrict__ bih1, const float* __restrict__ bhh1,
                       float* __restrict__ bsum0, float* __restrict__ bsum1) {
  int i = blockIdx.x * blockDim.x + threadIdx.x;
  if (i < G4_) {
    bsum0[i] = bih0[i] + bhh0[i];
    bsum1[i] = bih1[i] + bhh1[i];
  }
}

// initial h: layer0 -> h0buf parity 0, layer1 -> h1buf parity 1
__global__ void k_init2(const float* __restrict__ h0,
                        u16* __restrict__ h0buf, u16* __restrict__ h1buf) {
  int i = blockIdx.x * blockDim.x + threadIdx.x;
  int n = B_ * H_;
  if (i < n) {
    bf16 a = __float2bfloat16(h0[i]);
    bf16 b = __float2bfloat16(h0[n + i]);
    h0buf[i] = *reinterpret_cast<u16*>(&a);          // parity 0
    h1buf[n + i] = *reinterpret_cast<u16*>(&b);      // parity 1
  }
}

__global__ void k_zero(int* p) {
  int i = blockIdx.x * blockDim.x + threadIdx.x;
  if (i < 128) p[i] = 0;
}

// ---------------- persistent LSTM kernel ----------------
// 256 WGs x 512 thr (8 waves -> 2 waves/SIMD). XCD-locality mapping:
//   lb = wg & 7 : layer = lb>>2, bg = lb&3 ; cg = wg >> 3 (0..31)
// WG owns batch rows [bg*128,+128) x h-cols [cg*16,+16); wave w owns rows
// [bg*128 + w*16, +16), all 4 gates.
// Weights in LDS, FRAG-BLOCKED (conflict-free ds_read_b128): block fb = ni*32+s;
// within a block lane l holds W[gate ni, col hbase+(l&15)][s_local*32+(l>>4)*8+e]
// where s<16 -> W_ih (x-part), s>=16 -> W_hh (h-part).
// Per phase: hoist all 16 x-frags + 16 h-frags to regs (coherent loads issued
// together; x-MFMA sweep overlaps h-load latency), then two MFMA sweeps.
// Sync: per-bg pair-domain, per-layer counters (32 arrivals each), relaxed
// atomics, no cache-maintenance fences. c-state in regs; outputs deferred.
__global__ __launch_bounds__(512, 2)
void k_main(const u16* __restrict__ latb,
            const u16* __restrict__ W0i, const u16* __restrict__ W0h,
            const u16* __restrict__ W1i, const u16* __restrict__ W1h,
            const float* __restrict__ bs0, const float* __restrict__ bs1,
            const int* __restrict__ reset,   // (T,B)
            const float* __restrict__ c0,    // (2,B,H)
            u16* __restrict__ h0buf,         // [2][B][H]
            u16* __restrict__ h1buf,         // [2][B][H]
            float* __restrict__ hidden,      // (T,B,H)
            float* __restrict__ hn,          // (2,B,H)
            float* __restrict__ cn,          // (2,B,H)
            int* __restrict__ ctr) {         // 128 ints: [bg*32]=L0, [bg*32+16]=L1
  extern __shared__ char smem_raw[];
  u16* wlds = (u16*)smem_raw;                // 128KB frag-blocked weights
  __shared__ int rstlds[128];
  __shared__ float hstage[8][16][20];        // per-wave h packing tile

  const int tid   = threadIdx.x;
  const int wg    = blockIdx.x;
  const int lb    = wg & 7;
  const int layer = lb >> 2;
  const int bg    = lb & 3;
  const int cg    = wg >> 3;
  const int hbase = cg * 16;
  const int rowbase = bg * 128;
  const int wave  = tid >> 6;                  // 0..7
  const int lane  = tid & 63;
  const int r16   = lane & 15;
  const int kq    = lane >> 4;                 // 0..3
  const int wrow_local = wave * 16;            // wave's batch offset within WG
  const int wrow0 = rowbase + wrow_local;

  const u16* Wih = layer ? W1i : W0i;
  const u16* Whh = layer ? W1h : W0h;
  const float* bs = layer ? bs1 : bs0;
  u16* hself = layer ? h1buf : h0buf;
  int* ctrSelf  = ctr + bg * 32 + (layer ? 16 : 0);
  int* ctrOther = ctr + bg * 32 + (layer ? 0 : 16);

  // ---- stage weights into frag-blocked LDS (once) ----
  // chunk c = fb*64 + l ; fb = ni*32 + kslot ; kslot<16 -> W_ih, else W_hh
  // lane l holds W[gate ni, col hbase+(l&15)][kslot_local*32 + (l>>4)*8 .. +7]
  for (int it = 0; it < 16; ++it) {
    int c = it * 512 + tid;                    // 0..8191
    int fb = c >> 6, l = c & 63;
    int ni = fb >> 5, kslot = fb & 31;
    int col = hbase + (l & 15);
    int klocal = (kslot & 15) * 32 + (l >> 4) * 8;
    const u16* M = (kslot < 16) ? Wih : Whh;
    const u16* src = M + (size_t)(ni * H_ + col) * K_ + klocal;
    *(float4*)(wlds + ((size_t)c) * 8) = *(const float4*)src;
  }

  // per-lane gate biases (col = hbase + r16)
  float bias[4];
  #pragma unroll
  for (int g = 0; g < 4; ++g) bias[g] = bs[g * H_ + hbase + r16];

  // c-state registers: j -> row = wrow0 + kq*4 + j, col = hbase + r16
  float creg[4];
  #pragma unroll
  for (int j = 0; j < 4; ++j)
    creg[j] = c0[((size_t)layer * B_ + (wrow0 + kq * 4 + j)) * H_ + hbase + r16];

  __syncthreads();

  for (int p = 0; p <= T_; ++p) {
    const int t = layer ? (p - 1) : p;
    const bool active = (t >= 0 && t < T_);
    float hnew_r[4], cnew_r[4];

    if (active) {
      if (tid < 128) rstlds[tid] = reset[(size_t)t * B_ + rowbase + tid];
      __syncthreads();

      const u16* X  = layer ? (h0buf + (size_t)(p & 1) * B_ * H_)
                            : (latb + (size_t)t * B_ * K_);
      const u16* Hp = hself + (size_t)(p & 1) * B_ * H_;
      u16* Hn       = hself + (size_t)((p + 1) & 1) * B_ * H_;

      const int ra0 = rstlds[wrow_local + r16];
      const u16* x0  = X  + (size_t)(wrow0 + r16) * K_ + kq * 8;
      const u16* hp0 = Hp + (size_t)(wrow0 + r16) * H_ + kq * 8;

      // ---- hoist all A-frags: x first, then h (x-MFMA overlaps h latency) ----
      const frag zf = {};
      frag ax[16], ah[16];
      if (layer == 0) {
        #pragma unroll
        for (int s = 0; s < 16; ++s)
          ax[s] = *reinterpret_cast<const frag*>(x0 + s * 32);
      } else {
        #pragma unroll
        for (int s = 0; s < 16; ++s)
          ax[s] = ld_coh(x0 + s * 32);
      }
      #pragma unroll
      for (int s = 0; s < 16; ++s)
        ah[s] = ra0 ? zf : ld_coh(hp0 + s * 32);

      // ---- MFMA sweeps: conflict-free frag-blocked B reads ----
      f32x4 acc[4] = {};
      #pragma unroll
      for (int s = 0; s < 16; ++s) {
        #pragma unroll
        for (int ni = 0; ni < 4; ++ni) {
          frag b = *reinterpret_cast<const frag*>(
              wlds + ((size_t)((ni * 32 + s) * 64 + lane)) * 8);
          acc[ni] = __builtin_amdgcn_mfma_f32_16x16x32_bf16(ax[s], b, acc[ni], 0, 0, 0);
        }
      }
      #pragma unroll
      for (int s = 0; s < 16; ++s) {
        #pragma unroll
        for (int ni = 0; ni < 4; ++ni) {
          frag b = *reinterpret_cast<const frag*>(
              wlds + ((size_t)((ni * 32 + 16 + s) * 64 + lane)) * 8);
          acc[ni] = __builtin_amdgcn_mfma_f32_16x16x32_bf16(ah[s], b, acc[ni], 0, 0, 0);
        }
      }

      // cell elementwise: lane-local (4 outputs: rows kq*4+j, col r16)
      #pragma unroll
      for (int j = 0; j < 4; ++j) {
        const int lrow = wrow_local + kq * 4 + j;
        float gi = acc[0][j] + bias[0];
        float gf = acc[1][j] + bias[1];
        float gg = acc[2][j] + bias[2];
        float go = acc[3][j] + bias[3];
        float iv = 1.f / (1.f + __expf(-gi));
        float fv = 1.f / (1.f + __expf(-gf));
        float gv = 1.f - 2.f / (__expf(2.f * gg) + 1.f);   // tanh
        float ov = 1.f / (1.f + __expf(-go));
        float ce = rstlds[lrow] ? 0.f : creg[j];
        float cnew = fv * ce + iv * gv;
        float hnew = ov * (1.f - 2.f / (__expf(2.f * cnew) + 1.f));
        creg[j] = cnew;
        cnew_r[j] = cnew;
        hnew_r[j] = hnew;
        hstage[wave][kq * 4 + j][r16] = hnew;   // wave-local LDS
      }

      // pack + coherent h stores: lane -> (row = lane>>2, 4 cols at (lane&3)*4)
      {
        const int prow = lane >> 2;
        const int pc4  = lane & 3;
        float4 v = *reinterpret_cast<const float4*>(&hstage[wave][prow][pc4 * 4]);
        bf16 b0 = __float2bfloat16(v.x), b1 = __float2bfloat16(v.y);
        bf16 b2 = __float2bfloat16(v.z), b3 = __float2bfloat16(v.w);
        u64 pk = (u64)*reinterpret_cast<u16*>(&b0)
               | ((u64)*reinterpret_cast<u16*>(&b1) << 16)
               | ((u64)*reinterpret_cast<u16*>(&b2) << 32)
               | ((u64)*reinterpret_cast<u16*>(&b3) << 48);
        u16* dst = Hn + (size_t)(wrow0 + prow) * H_ + hbase + pc4 * 4;
        __hip_atomic_store((u64*)dst, pk, __ATOMIC_RELAXED, __HIP_MEMORY_SCOPE_AGENT);
      }
    }

    // barrier arrival (h stores drained first)
    if (p < T_) {
      asm volatile("s_waitcnt vmcnt(0)" ::: "memory");
      __syncthreads();
      if (tid == 0)
        __hip_atomic_fetch_add(ctrSelf, 1, __ATOMIC_RELAXED, __HIP_MEMORY_SCOPE_AGENT);
    }

    // deferred output stores (overlap with poll; nobody reads these in-kernel)
    if (active) {
      float* hidden_t = hidden + (size_t)t * B_ * H_;
      #pragma unroll
      for (int j = 0; j < 4; ++j) {
        const size_t off = (size_t)(wrow0 + kq * 4 + j) * H_ + hbase + r16;
        if (layer) hidden_t[off] = hnew_r[j];
        if (t == T_ - 1) {
          hn[(size_t)layer * B_ * H_ + off] = hnew_r[j];
          cn[(size_t)layer * B_ * H_ + off] = cnew_r[j];
        }
      }
    }

    // barrier wait: both layer counters of this pair-domain at phase p+1
    if (p < T_) {
      if (tid == 0) {
        const int target = 32 * (p + 1);
        while (true) {
          int a = __hip_atomic_load(ctrSelf,  __ATOMIC_RELAXED, __HIP_MEMORY_SCOPE_AGENT);
          int b = __hip_atomic_load(ctrOther, __ATOMIC_RELAXED, __HIP_MEMORY_SCOPE_AGENT);
          if (a >= target && b >= target) break;
          __builtin_amdgcn_s_sleep(2);
        }
      }
      __syncthreads();
    }
  }
}

// ---------------- host ----------------

extern "C" void kernel_launch(void* const* d_in, const int* in_sizes, int n_in,
                              void* d_out, int out_size, void* d_ws, size_t ws_size,
                              hipStream_t stream) {
  (void)in_sizes; (void)n_in; (void)out_size; (void)ws_size;

  const float* latent = (const float*)d_in[0];
  const float* h0in   = (const float*)d_in[1];
  const float* c0in   = (const float*)d_in[2];
  const int*   reset  = (const int*)d_in[3];
  const float* W_ih0  = (const float*)d_in[4];
  const float* W_hh0  = (const float*)d_in[5];
  const float* b_ih0  = (const float*)d_in[6];
  const float* b_hh0  = (const float*)d_in[7];
  const float* W_ih1  = (const float*)d_in[8];
  const float* W_hh1  = (const float*)d_in[9];
  const float* b_ih1  = (const float*)d_in[10];
  const float* b_hh1  = (const float*)d_in[11];

  float* out    = (float*)d_out;
  float* hidden = out;                               // (T,B,H)
  float* hn     = out + (size_t)T_ * B_ * H_;        // (2,B,H)
  float* cn     = hn + (size_t)2 * B_ * H_;          // (2,B,H)

  // workspace layout
  char* ws = (char*)d_ws;
  u16* latb  = (u16*)ws;                             // T*B*K bf16 (64 MiB)
  u16* wih0b = latb + (size_t)T_ * B_ * K_;
  u16* whh0b = wih0b + (size_t)G4_ * K_;
  u16* wih1b = whh0b + (size_t)G4_ * K_;
  u16* whh1b = wih1b + (size_t)G4_ * K_;
  float* bsum0 = (float*)(whh1b + (size_t)G4_ * K_);
  float* bsum1 = bsum0 + G4_;
  u16* h0buf = (u16*)(bsum1 + G4_);                  // [2][B][H]
  u16* h1buf = h0buf + (size_t)2 * B_ * H_;
  int* ctr   = (int*)(h1buf + (size_t)2 * B_ * H_);  // 128 ints

  // conversions / init (stream-ordered)
  int n_lat4 = T_ * B_ * K_ / 4;
  k_f32_to_bf16_v4<<<2048, 256, 0, stream>>>((const float4*)latent, (ushort4*)latb, n_lat4);
  int n_w4 = G4_ * K_ / 4;
  k_f32_to_bf16_v4<<<256, 256, 0, stream>>>((const float4*)W_ih0, (ushort4*)wih0b, n_w4);
  k_f32_to_bf16_v4<<<256, 256, 0, stream>>>((const float4*)W_hh0, (ushort4*)whh0b, n_w4);
  k_f32_to_bf16_v4<<<256, 256, 0, stream>>>((const float4*)W_ih1, (ushort4*)wih1b, n_w4);
  k_f32_to_bf16_v4<<<256, 256, 0, stream>>>((const float4*)W_hh1, (ushort4*)whh1b, n_w4);
  k_bias<<<(G4_ + 255) / 256, 256, 0, stream>>>(b_ih0, b_hh0, b_ih1, b_hh1, bsum0, bsum1);
  k_init2<<<(B_ * H_ + 255) / 256, 256, 0, stream>>>(h0in, h0buf, h1buf);
  k_zero<<<1, 128, 0, stream>>>(ctr);

  // persistent cooperative kernel
  hipFuncSetAttribute((const void*)k_main, hipFuncAttributeMaxDynamicSharedMemorySize,
                      (int)SMEM_BYTES);
  void* args[] = { (void*)&latb, (void*)&wih0b, (void*)&whh0b, (void*)&wih1b, (void*)&whh1b,
                   (void*)&bsum0, (void*)&bsum1, (void*)&reset, (void*)&c0in,
                   (void*)&h0buf, (void*)&h1buf, (void*)&hidden, (void*)&hn, (void*)&cn,
                   (void*)&ctr };
  hipLaunchCooperativeKernel((void*)k_main, dim3(NWG), dim3(512), args,
                             (unsigned int)SMEM_BYTES, stream);
}

// Round 10
// 1799.349 us; speedup vs baseline: 1.4213x; 1.1663x over previous
//
#include <hip/hip_runtime.h>
#include <hip/hip_bf16.h>

typedef __hip_bfloat16 bf16;
typedef unsigned short u16;
typedef unsigned long long u64;
using frag  = __attribute__((ext_vector_type(8))) short;   // 8 bf16
using f32x4 = __attribute__((ext_vector_type(4))) float;   // 4 fp32 acc

static constexpr int T_  = 128;
static constexpr int B_  = 512;
static constexpr int H_  = 512;
static constexpr int K_  = 512;
static constexpr int G4_ = 2048;
static constexpr int NWG = 256;

// dynamic LDS: frag-blocked weights only (128 blocks x 1KB)
static constexpr size_t W_BYTES = 131072;
static constexpr size_t SMEM_BYTES = W_BYTES;

// coherent (agent-scope, L1/L2-bypassing) 16B load as 2x b64 relaxed atomics
__device__ __forceinline__ frag ld_coh(const u16* p) {
  u64 lo = __hip_atomic_load((const u64*)p,       __ATOMIC_RELAXED, __HIP_MEMORY_SCOPE_AGENT);
  u64 hi = __hip_atomic_load((const u64*)(p + 4), __ATOMIC_RELAXED, __HIP_MEMORY_SCOPE_AGENT);
  union { u64 q[2]; frag f; } u;
  u.q[0] = lo; u.q[1] = hi;
  return u.f;
}

// ---------------- setup kernels ----------------

__global__ void k_f32_to_bf16_v4(const float4* __restrict__ src,
                                 ushort4* __restrict__ dst, int n4) {
  int i = blockIdx.x * blockDim.x + threadIdx.x;
  int stride = gridDim.x * blockDim.x;
  for (; i < n4; i += stride) {
    float4 v = src[i];
    ushort4 o;
    bf16 t0 = __float2bfloat16(v.x); o.x = *reinterpret_cast<u16*>(&t0);
    bf16 t1 = __float2bfloat16(v.y); o.y = *reinterpret_cast<u16*>(&t1);
    bf16 t2 = __float2bfloat16(v.z); o.z = *reinterpret_cast<u16*>(&t2);
    bf16 t3 = __float2bfloat16(v.w); o.w = *reinterpret_cast<u16*>(&t3);
    dst[i] = o;
  }
}

__global__ void k_bias(const float* __restrict__ bih0, const float* __restrict__ bhh0,
                       const float* __restrict__ bih1, const float* __restrict__ bhh1,
                       float* __restrict__ bsum0, float* __restrict__ bsum1) {
  int i = blockIdx.x * blockDim.x + threadIdx.x;
  if (i < G4_) {
    bsum0[i] = bih0[i] + bhh0[i];
    bsum1[i] = bih1[i] + bhh1[i];
  }
}

// initial h: layer0 -> h0buf parity 0, layer1 -> h1buf parity 1
__global__ void k_init2(const float* __restrict__ h0,
                        u16* __restrict__ h0buf, u16* __restrict__ h1buf) {
  int i = blockIdx.x * blockDim.x + threadIdx.x;
  int n = B_ * H_;
  if (i < n) {
    bf16 a = __float2bfloat16(h0[i]);
    bf16 b = __float2bfloat16(h0[n + i]);
    h0buf[i] = *reinterpret_cast<u16*>(&a);          // parity 0
    h1buf[n + i] = *reinterpret_cast<u16*>(&b);      // parity 1
  }
}

__global__ void k_zero(int* p) {
  int i = blockIdx.x * blockDim.x + threadIdx.x;
  if (i < 256) p[i] = 0;
}

// ---------------- persistent LSTM kernel ----------------
// 256 WGs x 512 thr (8 waves -> 2 waves/SIMD). XCD-locality mapping:
//   lb = wg & 7 : layer = lb>>2, bg = lb&3 ; cg = wg >> 3 (0..31)
// WG owns batch rows [bg*128,+128) x h-cols [cg*16,+16); wave w owns rows
// [bg*128 + w*16, +16), all 4 gates. (R6 structure.)
// Weights in LDS, FRAG-BLOCKED (conflict-free ds_read_b128): block fb = ni*32+s
// (s<16: W_ih slice s; s>=16: W_hh slice s-16); within a block, lane l holds
// W[gate ni, col hbase+(l&15)][s_local*32 + (l>>4)*8 .. +7] (16B, lane-consecutive).
// Sync: FLAG ARRAY — WG wg stores phase# to arr[wg] (own slot, no RMW);
// wave 0's 64 lanes poll the 64 slots of the (bg) pair domain in parallel.
// No cache-maintenance fences: cross-WG h moves via agent-scope relaxed atomics.
// c-state in regs; hidden/hn/cn stores deferred past flag store.
__global__ __launch_bounds__(512, 2)
void k_main(const u16* __restrict__ latb,
            const u16* __restrict__ W0i, const u16* __restrict__ W0h,
            const u16* __restrict__ W1i, const u16* __restrict__ W1h,
            const float* __restrict__ bs0, const float* __restrict__ bs1,
            const int* __restrict__ reset,   // (T,B)
            const float* __restrict__ c0,    // (2,B,H)
            u16* __restrict__ h0buf,         // [2][B][H]
            u16* __restrict__ h1buf,         // [2][B][H]
            float* __restrict__ hidden,      // (T,B,H)
            float* __restrict__ hn,          // (2,B,H)
            float* __restrict__ cn,          // (2,B,H)
            int* __restrict__ arr) {         // 256 flag slots, one per WG
  extern __shared__ char smem_raw[];
  u16* wlds = (u16*)smem_raw;                // 128KB frag-blocked weights
  __shared__ float hstage[8][16][20];        // per-wave h packing tile

  const int tid   = threadIdx.x;
  const int wg    = blockIdx.x;
  const int lb    = wg & 7;
  const int layer = lb >> 2;
  const int bg    = lb & 3;
  const int cg    = wg >> 3;
  const int hbase = cg * 16;
  const int rowbase = bg * 128;
  const int wave  = tid >> 6;                  // 0..7
  const int lane  = tid & 63;
  const int r16   = lane & 15;
  const int kq    = lane >> 4;                 // 0..3
  const int wrow_local = wave * 16;            // wave's batch offset within WG
  const int wrow0 = rowbase + wrow_local;

  const u16* Wih = layer ? W1i : W0i;
  const u16* Whh = layer ? W1h : W0h;
  const float* bs = layer ? bs1 : bs0;
  u16* hself = layer ? h1buf : h0buf;

  // ---- stage weights into frag-blocked LDS (once) ----
  // chunk c = fb*64 + l ; fb = ni*32 + kslot ; kslot<16 -> W_ih, else W_hh
  for (int it = 0; it < 16; ++it) {
    int c = it * 512 + tid;                    // 0..8191
    int fb = c >> 6, l = c & 63;
    int ni = fb >> 5, kslot = fb & 31;
    int col = hbase + (l & 15);
    int klocal = (kslot & 15) * 32 + (l >> 4) * 8;
    const u16* M = (kslot < 16) ? Wih : Whh;
    const u16* src = M + (size_t)(ni * H_ + col) * K_ + klocal;
    *(float4*)(wlds + ((size_t)c) * 8) = *(const float4*)src;
  }

  // per-lane gate biases (col = hbase + r16)
  float bias[4];
  #pragma unroll
  for (int g = 0; g < 4; ++g) bias[g] = bs[g * H_ + hbase + r16];

  // c-state registers: j -> row = wrow0 + kq*4 + j, col = hbase + r16
  float creg[4];
  #pragma unroll
  for (int j = 0; j < 4; ++j)
    creg[j] = c0[((size_t)layer * B_ + (wrow0 + kq * 4 + j)) * H_ + hbase + r16];

  __syncthreads();

  for (int p = 0; p <= T_; ++p) {
    const int t = layer ? (p - 1) : p;
    const bool active = (t >= 0 && t < T_);
    float hnew_r[4], cnew_r[4];

    if (active) {
      const u16* X  = layer ? (h0buf + (size_t)(p & 1) * B_ * H_)
                            : (latb + (size_t)t * B_ * K_);
      const u16* Hp = hself + (size_t)(p & 1) * B_ * H_;
      u16* Hn       = hself + (size_t)((p + 1) & 1) * B_ * H_;

      const int* rst_t = reset + (size_t)t * B_;
      const int ra0 = rst_t[wrow0 + r16];           // mask for this lane's A row
      const u16* x0  = X  + (size_t)(wrow0 + r16) * K_ + kq * 8;
      const u16* hp0 = Hp + (size_t)(wrow0 + r16) * H_ + kq * 8;

      f32x4 acc[4] = {};
      const frag zf = {};

      // merged x+h K-loop, in-loop loads (compiler-scheduled), frag-blocked B
      if (layer == 0) {
        #pragma unroll
        for (int s = 0; s < 16; ++s) {
          frag a  = *reinterpret_cast<const frag*>(x0 + s * 32);
          frag ah = ra0 ? zf : ld_coh(hp0 + s * 32);
          #pragma unroll
          for (int ni = 0; ni < 4; ++ni) {
            frag bx = *reinterpret_cast<const frag*>(
                wlds + ((size_t)((ni * 32 + s) * 64 + lane)) * 8);
            frag bh = *reinterpret_cast<const frag*>(
                wlds + ((size_t)((ni * 32 + 16 + s) * 64 + lane)) * 8);
            acc[ni] = __builtin_amdgcn_mfma_f32_16x16x32_bf16(a,  bx, acc[ni], 0, 0, 0);
            acc[ni] = __builtin_amdgcn_mfma_f32_16x16x32_bf16(ah, bh, acc[ni], 0, 0, 0);
          }
        }
      } else {
        #pragma unroll
        for (int s = 0; s < 16; ++s) {
          frag a  = ld_coh(x0 + s * 32);
          frag ah = ra0 ? zf : ld_coh(hp0 + s * 32);
          #pragma unroll
          for (int ni = 0; ni < 4; ++ni) {
            frag bx = *reinterpret_cast<const frag*>(
                wlds + ((size_t)((ni * 32 + s) * 64 + lane)) * 8);
            frag bh = *reinterpret_cast<const frag*>(
                wlds + ((size_t)((ni * 32 + 16 + s) * 64 + lane)) * 8);
            acc[ni] = __builtin_amdgcn_mfma_f32_16x16x32_bf16(a,  bx, acc[ni], 0, 0, 0);
            acc[ni] = __builtin_amdgcn_mfma_f32_16x16x32_bf16(ah, bh, acc[ni], 0, 0, 0);
          }
        }
      }

      // cell elementwise: lane-local (4 outputs: rows kq*4+j, col r16)
      #pragma unroll
      for (int j = 0; j < 4; ++j) {
        const int rstj = rst_t[wrow0 + kq * 4 + j];
        float gi = acc[0][j] + bias[0];
        float gf = acc[1][j] + bias[1];
        float gg = acc[2][j] + bias[2];
        float go = acc[3][j] + bias[3];
        float iv = 1.f / (1.f + __expf(-gi));
        float fv = 1.f / (1.f + __expf(-gf));
        float gv = 1.f - 2.f / (__expf(2.f * gg) + 1.f);   // tanh
        float ov = 1.f / (1.f + __expf(-go));
        float ce = rstj ? 0.f : creg[j];
        float cnew = fv * ce + iv * gv;
        float hnew = ov * (1.f - 2.f / (__expf(2.f * cnew) + 1.f));
        creg[j] = cnew;
        cnew_r[j] = cnew;
        hnew_r[j] = hnew;
        hstage[wave][kq * 4 + j][r16] = hnew;   // wave-local LDS (in-wave ordering)
      }

      // pack + coherent h stores: lane -> (row = lane>>2, 4 cols at (lane&3)*4)
      {
        const int prow = lane >> 2;
        const int pc4  = lane & 3;
        float4 v = *reinterpret_cast<const float4*>(&hstage[wave][prow][pc4 * 4]);
        bf16 b0 = __float2bfloat16(v.x), b1 = __float2bfloat16(v.y);
        bf16 b2 = __float2bfloat16(v.z), b3 = __float2bfloat16(v.w);
        u64 pk = (u64)*reinterpret_cast<u16*>(&b0)
               | ((u64)*reinterpret_cast<u16*>(&b1) << 16)
               | ((u64)*reinterpret_cast<u16*>(&b2) << 32)
               | ((u64)*reinterpret_cast<u16*>(&b3) << 48);
        u16* dst = Hn + (size_t)(wrow0 + prow) * H_ + hbase + pc4 * 4;
        __hip_atomic_store((u64*)dst, pk, __ATOMIC_RELAXED, __HIP_MEMORY_SCOPE_AGENT);
      }
    }

    // barrier arrival: own-slot flag store (no RMW), after h stores acked
    if (p < T_) {
      asm volatile("s_waitcnt vmcnt(0)" ::: "memory");
      __syncthreads();
      if (tid == 0)
        __hip_atomic_store(arr + wg, p + 1, __ATOMIC_RELAXED, __HIP_MEMORY_SCOPE_AGENT);
    }

    // deferred output stores (overlap with poll; nobody reads these in-kernel)
    if (active) {
      float* hidden_t = hidden + (size_t)t * B_ * H_;
      #pragma unroll
      for (int j = 0; j < 4; ++j) {
        const size_t off = (size_t)(wrow0 + kq * 4 + j) * H_ + hbase + r16;
        if (layer) hidden_t[off] = hnew_r[j];
        if (t == T_ - 1) {
          hn[(size_t)layer * B_ * H_ + off] = hnew_r[j];
          cn[(size_t)layer * B_ * H_ + off] = cnew_r[j];
        }
      }
    }

    // barrier wait: wave 0's 64 lanes poll the 64 pair-domain slots in parallel
    if (p < T_) {
      if (wave == 0) {
        const int slot = (lane >> 1) * 8 + (lane & 1) * 4 + bg;  // all 64 domain WGs
        while (__hip_atomic_load(arr + slot, __ATOMIC_RELAXED,
                                 __HIP_MEMORY_SCOPE_AGENT) < p + 1)
          __builtin_amdgcn_s_sleep(2);
      }
      __syncthreads();
    }
  }
}

// ---------------- host ----------------

extern "C" void kernel_launch(void* const* d_in, const int* in_sizes, int n_in,
                              void* d_out, int out_size, void* d_ws, size_t ws_size,
                              hipStream_t stream) {
  (void)in_sizes; (void)n_in; (void)out_size; (void)ws_size;

  const float* latent = (const float*)d_in[0];
  const float* h0in   = (const float*)d_in[1];
  const float* c0in   = (const float*)d_in[2];
  const int*   reset  = (const int*)d_in[3];
  const float* W_ih0  = (const float*)d_in[4];
  const float* W_hh0  = (const float*)d_in[5];
  const float* b_ih0  = (const float*)d_in[6];
  const float* b_hh0  = (const float*)d_in[7];
  const float* W_ih1  = (const float*)d_in[8];
  const float* W_hh1  = (const float*)d_in[9];
  const float* b_ih1  = (const float*)d_in[10];
  const float* b_hh1  = (const float*)d_in[11];

  float* out    = (float*)d_out;
  float* hidden = out;                               // (T,B,H)
  float* hn     = out + (size_t)T_ * B_ * H_;        // (2,B,H)
  float* cn     = hn + (size_t)2 * B_ * H_;          // (2,B,H)

  // workspace layout
  char* ws = (char*)d_ws;
  u16* latb  = (u16*)ws;                             // T*B*K bf16 (64 MiB)
  u16* wih0b = latb + (size_t)T_ * B_ * K_;
  u16* whh0b = wih0b + (size_t)G4_ * K_;
  u16* wih1b = whh0b + (size_t)G4_ * K_;
  u16* whh1b = wih1b + (size_t)G4_ * K_;
  float* bsum0 = (float*)(whh1b + (size_t)G4_ * K_);
  float* bsum1 = bsum0 + G4_;
  u16* h0buf = (u16*)(bsum1 + G4_);                  // [2][B][H]
  u16* h1buf = h0buf + (size_t)2 * B_ * H_;
  int* arr   = (int*)(h1buf + (size_t)2 * B_ * H_);  // 256 flag slots

  // conversions / init (stream-ordered)
  int n_lat4 = T_ * B_ * K_ / 4;
  k_f32_to_bf16_v4<<<2048, 256, 0, stream>>>((const float4*)latent, (ushort4*)latb, n_lat4);
  int n_w4 = G4_ * K_ / 4;
  k_f32_to_bf16_v4<<<256, 256, 0, stream>>>((const float4*)W_ih0, (ushort4*)wih0b, n_w4);
  k_f32_to_bf16_v4<<<256, 256, 0, stream>>>((const float4*)W_hh0, (ushort4*)whh0b, n_w4);
  k_f32_to_bf16_v4<<<256, 256, 0, stream>>>((const float4*)W_ih1, (ushort4*)wih1b, n_w4);
  k_f32_to_bf16_v4<<<256, 256, 0, stream>>>((const float4*)W_hh1, (ushort4*)whh1b, n_w4);
  k_bias<<<(G4_ + 255) / 256, 256, 0, stream>>>(b_ih0, b_hh0, b_ih1, b_hh1, bsum0, bsum1);
  k_init2<<<(B_ * H_ + 255) / 256, 256, 0, stream>>>(h0in, h0buf, h1buf);
  k_zero<<<1, 256, 0, stream>>>(arr);

  // persistent cooperative kernel
  hipFuncSetAttribute((const void*)k_main, hipFuncAttributeMaxDynamicSharedMemorySize,
                      (int)SMEM_BYTES);
  void* args[] = { (void*)&latb, (void*)&wih0b, (void*)&whh0b, (void*)&wih1b, (void*)&whh1b,
                   (void*)&bsum0, (void*)&bsum1, (void*)&reset, (void*)&c0in,
                   (void*)&h0buf, (void*)&h1buf, (void*)&hidden, (void*)&hn, (void*)&cn,
                   (void*)&arr };
  hipLaunchCooperativeKernel((void*)k_main, dim3(NWG), dim3(512), args,
                             (unsigned int)SMEM_BYTES, stream);
}